// Round 5
// baseline (211.117 us; speedup 1.0000x reference)
//
#include <hip/hip_runtime.h>

// UnaryLinear (UnarySim stochastic linear), one clock, batch=1.
// out[o] = (acc[o] + sum_i f(i,o) + b_bit[o]) >= acc_bound
//   f = x[i] ? (w[o,i] >= brev8(rwi[o,i])) : !(w[o,i] >= brev8(rwii[o,i]))
// Sobol table closed form: rng[i] == bitreverse8(i)  (verified R4, absmax=0).
//
// R4 lesson: latency-bound at 1024 blocks (16 waves/CU, 34% occ, 2.5 TB/s eff).
// Now: 1 row per 256-thread block (grid 4096 -> 32 waves/CU), 4 waves split
// the row, full unroll for ~12 outstanding 16B loads/wave, VGPR<=64 via
// __launch_bounds__(256,8).

constexpr int IN_F  = 4096;
constexpr int OUT_F = 4096;

__global__ __launch_bounds__(256, 8) void unary_linear_kernel(
    const float* __restrict__ x,            // [IN_F] in {0,1}
    const float* __restrict__ buf_wght,     // [OUT_F, IN_F]
    const float* __restrict__ buf_bias,     // [OUT_F]
    const float* __restrict__ acc,          // [OUT_F]
    const float* __restrict__ acc_bound,    // [1] = IN_F+1
    const int*   __restrict__ rng_wght_idx,     // [OUT_F, IN_F] in [0,256)
    const int*   __restrict__ rng_bias_idx,     // [OUT_F]
    const int*   __restrict__ rng_wght_idx_inv, // [OUT_F, IN_F]
    float*       __restrict__ out)          // [OUT_F]
{
    const int row  = blockIdx.x;
    const int tid  = threadIdx.x;           // 0..255
    const int wave = tid >> 6;
    const int lane = tid & 63;

    const float* __restrict__ wrow = buf_wght         + (size_t)row * IN_F;
    const int*   __restrict__ irow = rng_wght_idx     + (size_t)row * IN_F;
    const int*   __restrict__ vrow = rng_wght_idx_inv + (size_t)row * IN_F;

    float sum = 0.0f;

    // 4096 elems / 256 threads = 16 elems/thread = 4 x float4. Full unroll:
    // up to 12 independent 16B streaming loads in flight per wave.
    #pragma unroll
    for (int i = 0; i < 4; ++i) {
        const int base = (i * 256 + tid) * 4;   // coalesced: 1 KB/wave/iter
        const float4 w  = *reinterpret_cast<const float4*>(wrow + base);
        const int4   ii = *reinterpret_cast<const int4*>(irow + base);
        const int4   vi = *reinterpret_cast<const int4*>(vrow + base);
        const float4 xv = *reinterpret_cast<const float4*>(x + base);

        {
            const float r  = (float)(__brev((unsigned)ii.x) >> 24);
            const float ri = (float)(__brev((unsigned)vi.x) >> 24);
            sum += (xv.x != 0.0f) ? ((w.x >= r) ? 1.0f : 0.0f)
                                  : ((w.x >= ri) ? 0.0f : 1.0f);
        }
        {
            const float r  = (float)(__brev((unsigned)ii.y) >> 24);
            const float ri = (float)(__brev((unsigned)vi.y) >> 24);
            sum += (xv.y != 0.0f) ? ((w.y >= r) ? 1.0f : 0.0f)
                                  : ((w.y >= ri) ? 0.0f : 1.0f);
        }
        {
            const float r  = (float)(__brev((unsigned)ii.z) >> 24);
            const float ri = (float)(__brev((unsigned)vi.z) >> 24);
            sum += (xv.z != 0.0f) ? ((w.z >= r) ? 1.0f : 0.0f)
                                  : ((w.z >= ri) ? 0.0f : 1.0f);
        }
        {
            const float r  = (float)(__brev((unsigned)ii.w) >> 24);
            const float ri = (float)(__brev((unsigned)vi.w) >> 24);
            sum += (xv.w != 0.0f) ? ((w.w >= r) ? 1.0f : 0.0f)
                                  : ((w.w >= ri) ? 0.0f : 1.0f);
        }
    }

    // wave-level butterfly reduce (64 lanes)
    #pragma unroll
    for (int off = 32; off > 0; off >>= 1)
        sum += __shfl_down(sum, off);

    // cross-wave reduce via 4-slot LDS (no bank-conflict concern)
    __shared__ float wsum[4];
    if (lane == 0) wsum[wave] = sum;
    __syncthreads();

    if (tid == 0) {
        const float rb = (float)(__brev((unsigned)rng_bias_idx[row]) >> 24);
        const float b_bit = (buf_bias[row] >= rb) ? 1.0f : 0.0f;
        const float total = acc[row] + wsum[0] + wsum[1] + wsum[2] + wsum[3] + b_bit;
        out[row] = (total >= acc_bound[0]) ? 1.0f : 0.0f;
    }
}

extern "C" void kernel_launch(void* const* d_in, const int* in_sizes, int n_in,
                              void* d_out, int out_size, void* d_ws, size_t ws_size,
                              hipStream_t stream)
{
    // setup_inputs() order:
    // 0:x 1:buf_wght 2:buf_bias 3:rng 4:acc 5:acc_bound
    // 6:rng_wght_idx 7:rng_bias_idx 8:rng_wght_idx_inv
    const float* x         = (const float*)d_in[0];
    const float* buf_wght  = (const float*)d_in[1];
    const float* buf_bias  = (const float*)d_in[2];
    // d_in[3] = rng table — unused (closed form: rng[i] == bitreverse8(i))
    const float* acc       = (const float*)d_in[4];
    const float* acc_bound = (const float*)d_in[5];
    const int*   rwi       = (const int*)d_in[6];
    const int*   rbi       = (const int*)d_in[7];
    const int*   rwii      = (const int*)d_in[8];
    float* out = (float*)d_out;

    dim3 grid(OUT_F);       // 4096 blocks: 1 row per block, ~8 blocks/CU
    dim3 block(256);
    hipLaunchKernelGGL(unary_linear_kernel, grid, block, 0, stream,
                       x, buf_wght, buf_bias, acc, acc_bound,
                       rwi, rbi, rwii, out);
}

// Round 6
// 207.047 us; speedup vs baseline: 1.0197x; 1.0197x over previous
//
#include <hip/hip_runtime.h>

// UnaryLinear (UnarySim stochastic linear), one clock, batch=1.
// out[o] = (acc[o] + sum_i f(i,o) + b_bit[o]) >= acc_bound
//   f = x[i] ? (w[o,i] >= brev8(rwi[o,i])) : !(w[o,i] >= brev8(rwii[o,i]))
// Sobol closed form rng[i] == bitreverse8(i): verified R4 (absmax = 0).
//
// R5 lesson: latency/MLP-bound. launch_bounds(256,8) -> VGPR=20 -> ~2 loads
// in flight/wave; waves x in-flight product unchanged vs R4 -> same 78 us.
// Now: batch-issue ALL 16 independent 16B loads per thread into registers
// (64 VGPR of load data), THEN consume. launch_bounds(256,4) caps VGPR at
// 128 (no spill), giving ~5-6 waves/SIMD with ~16 loads in flight each:
// ~5-6 KB/CU outstanding vs ~1 KB before.

constexpr int IN_F  = 4096;
constexpr int OUT_F = 4096;

__global__ __launch_bounds__(256, 4) void unary_linear_kernel(
    const float* __restrict__ x,            // [IN_F] in {0,1}
    const float* __restrict__ buf_wght,     // [OUT_F, IN_F]
    const float* __restrict__ buf_bias,     // [OUT_F]
    const float* __restrict__ acc,          // [OUT_F]
    const float* __restrict__ acc_bound,    // [1] = IN_F+1
    const int*   __restrict__ rng_wght_idx,     // [OUT_F, IN_F] in [0,256)
    const int*   __restrict__ rng_bias_idx,     // [OUT_F]
    const int*   __restrict__ rng_wght_idx_inv, // [OUT_F, IN_F]
    float*       __restrict__ out)          // [OUT_F]
{
    const int row  = blockIdx.x;
    const int tid  = threadIdx.x;           // 0..255
    const int wave = tid >> 6;
    const int lane = tid & 63;

    const float* __restrict__ wrow = buf_wght         + (size_t)row * IN_F;
    const int*   __restrict__ irow = rng_wght_idx     + (size_t)row * IN_F;
    const int*   __restrict__ vrow = rng_wght_idx_inv + (size_t)row * IN_F;

    // ---- load phase: issue all 16 x 16B loads, no consumption in between ----
    float4 w[4];
    int4   ii[4];
    int4   vi[4];
    float4 xv[4];
    #pragma unroll
    for (int i = 0; i < 4; ++i) {           // unroll-constant indices -> regs
        const int base = (i * 256 + tid) * 4;
        w[i]  = *reinterpret_cast<const float4*>(wrow + base);
        ii[i] = *reinterpret_cast<const int4*>(irow + base);
        vi[i] = *reinterpret_cast<const int4*>(vrow + base);
        xv[i] = *reinterpret_cast<const float4*>(x + base);
    }

    // ---- compute phase ----
    float sum = 0.0f;
    #pragma unroll
    for (int i = 0; i < 4; ++i) {
        {
            const float r  = (float)(__brev((unsigned)ii[i].x) >> 24);
            const float ri = (float)(__brev((unsigned)vi[i].x) >> 24);
            sum += (xv[i].x != 0.0f) ? ((w[i].x >= r) ? 1.0f : 0.0f)
                                     : ((w[i].x >= ri) ? 0.0f : 1.0f);
        }
        {
            const float r  = (float)(__brev((unsigned)ii[i].y) >> 24);
            const float ri = (float)(__brev((unsigned)vi[i].y) >> 24);
            sum += (xv[i].y != 0.0f) ? ((w[i].y >= r) ? 1.0f : 0.0f)
                                     : ((w[i].y >= ri) ? 0.0f : 1.0f);
        }
        {
            const float r  = (float)(__brev((unsigned)ii[i].z) >> 24);
            const float ri = (float)(__brev((unsigned)vi[i].z) >> 24);
            sum += (xv[i].z != 0.0f) ? ((w[i].z >= r) ? 1.0f : 0.0f)
                                     : ((w[i].z >= ri) ? 0.0f : 1.0f);
        }
        {
            const float r  = (float)(__brev((unsigned)ii[i].w) >> 24);
            const float ri = (float)(__brev((unsigned)vi[i].w) >> 24);
            sum += (xv[i].w != 0.0f) ? ((w[i].w >= r) ? 1.0f : 0.0f)
                                     : ((w[i].w >= ri) ? 0.0f : 1.0f);
        }
    }

    // wave-level butterfly reduce (64 lanes)
    #pragma unroll
    for (int off = 32; off > 0; off >>= 1)
        sum += __shfl_down(sum, off);

    // cross-wave reduce via 4-slot LDS
    __shared__ float wsum[4];
    if (lane == 0) wsum[wave] = sum;
    __syncthreads();

    if (tid == 0) {
        const float rb = (float)(__brev((unsigned)rng_bias_idx[row]) >> 24);
        const float b_bit = (buf_bias[row] >= rb) ? 1.0f : 0.0f;
        const float total = acc[row] + wsum[0] + wsum[1] + wsum[2] + wsum[3] + b_bit;
        out[row] = (total >= acc_bound[0]) ? 1.0f : 0.0f;
    }
}

extern "C" void kernel_launch(void* const* d_in, const int* in_sizes, int n_in,
                              void* d_out, int out_size, void* d_ws, size_t ws_size,
                              hipStream_t stream)
{
    // setup_inputs() order:
    // 0:x 1:buf_wght 2:buf_bias 3:rng 4:acc 5:acc_bound
    // 6:rng_wght_idx 7:rng_bias_idx 8:rng_wght_idx_inv
    const float* x         = (const float*)d_in[0];
    const float* buf_wght  = (const float*)d_in[1];
    const float* buf_bias  = (const float*)d_in[2];
    // d_in[3] = rng table — unused (closed form: rng[i] == bitreverse8(i))
    const float* acc       = (const float*)d_in[4];
    const float* acc_bound = (const float*)d_in[5];
    const int*   rwi       = (const int*)d_in[6];
    const int*   rbi       = (const int*)d_in[7];
    const int*   rwii      = (const int*)d_in[8];
    float* out = (float*)d_out;

    dim3 grid(OUT_F);       // 4096 blocks: 1 row per block
    dim3 block(256);
    hipLaunchKernelGGL(unary_linear_kernel, grid, block, 0, stream,
                       x, buf_wght, buf_bias, acc, acc_bound,
                       rwi, rbi, rwii, out);
}

// Round 7
// 206.595 us; speedup vs baseline: 1.0219x; 1.0022x over previous
//
#include <hip/hip_runtime.h>
#include <stdint.h>

// UnaryLinear (UnarySim stochastic linear), one clock, batch=1.
// out[o] = (acc[o] + sum_i f(i,o) + b_bit[o]) >= acc_bound
//   f = x[i] ? (w[o,i] >= brev8(rwi[o,i])) : !(w[o,i] >= brev8(rwii[o,i]))
// Sobol closed form rng[i] == bitreverse8(i): verified R4 (absmax = 0).
//
// R5/R6 lesson: MLP-bound; hipcc sinks loads and minimizes VGPR (36) no
// matter how the source is phrased -> ~1KB in flight/CU -> 2.6 TB/s wall.
// Fix: ONE volatile asm block issues all 16 global_load_dwordx4 (compiler
// cannot split/sink it), staged consumption with counted s_waitcnt
// vmcnt(12/8/4/0), each followed by sched_barrier(0) (rule #18: consumers
// depend on the load asm, not the waitcnt -> must fence).

constexpr int IN_F  = 4096;
constexpr int OUT_F = 4096;

typedef float v4f __attribute__((ext_vector_type(4)));
typedef int   v4i __attribute__((ext_vector_type(4)));

__device__ __forceinline__ float contrib(float w, int ii, int vi, float xf) {
    const float r  = (float)(__brev((unsigned)ii) >> 24);
    const float ri = (float)(__brev((unsigned)vi) >> 24);
    return (xf != 0.0f) ? ((w >= r) ? 1.0f : 0.0f)
                        : ((w >= ri) ? 0.0f : 1.0f);
}

__global__ __launch_bounds__(256, 4) void unary_linear_kernel(
    const float* __restrict__ x,            // [IN_F] in {0,1}
    const float* __restrict__ buf_wght,     // [OUT_F, IN_F]
    const float* __restrict__ buf_bias,     // [OUT_F]
    const float* __restrict__ acc,          // [OUT_F]
    const float* __restrict__ acc_bound,    // [1] = IN_F+1
    const int*   __restrict__ rng_wght_idx,     // [OUT_F, IN_F] in [0,256)
    const int*   __restrict__ rng_bias_idx,     // [OUT_F]
    const int*   __restrict__ rng_wght_idx_inv, // [OUT_F, IN_F]
    float*       __restrict__ out)          // [OUT_F]
{
    const int row  = blockIdx.x;
    const int tid  = threadIdx.x;           // 0..255
    const int wave = tid >> 6;
    const int lane = tid & 63;

    const char* wrow = (const char*)(buf_wght         + (size_t)row * IN_F);
    const char* irow = (const char*)(rng_wght_idx     + (size_t)row * IN_F);
    const char* vrow = (const char*)(rng_wght_idx_inv + (size_t)row * IN_F);
    const char* xrow = (const char*)x;

    // Group g covers row bytes [g*4096 + tid*16, +16).  Two bases per array
    // (+4KB, +12KB) so signed-13-bit imm offsets {-4096, 0} reach all 4 groups.
    const uint64_t wb0 = (uint64_t)(wrow + 4096 + (size_t)tid * 16);
    const uint64_t wb1 = wb0 + 8192;
    const uint64_t ib0 = (uint64_t)(irow + 4096 + (size_t)tid * 16);
    const uint64_t ib1 = ib0 + 8192;
    const uint64_t vb0 = (uint64_t)(vrow + 4096 + (size_t)tid * 16);
    const uint64_t vb1 = vb0 + 8192;
    const uint64_t xb0 = (uint64_t)(xrow + 4096 + (size_t)tid * 16);
    const uint64_t xb1 = xb0 + 8192;

    v4f w0, w1, w2, w3, x0, x1, x2, x3;
    v4i i0, i1, i2, i3, v0, v1, v2, v3;

    // Issue ALL 16 loads back-to-back; issue order = (g0, g1, g2, g3).
    asm volatile(
        "global_load_dwordx4 %0,  %16, off offset:-4096\n\t"
        "global_load_dwordx4 %1,  %18, off offset:-4096\n\t"
        "global_load_dwordx4 %2,  %20, off offset:-4096\n\t"
        "global_load_dwordx4 %3,  %22, off offset:-4096\n\t"
        "global_load_dwordx4 %4,  %16, off\n\t"
        "global_load_dwordx4 %5,  %18, off\n\t"
        "global_load_dwordx4 %6,  %20, off\n\t"
        "global_load_dwordx4 %7,  %22, off\n\t"
        "global_load_dwordx4 %8,  %17, off offset:-4096\n\t"
        "global_load_dwordx4 %9,  %19, off offset:-4096\n\t"
        "global_load_dwordx4 %10, %21, off offset:-4096\n\t"
        "global_load_dwordx4 %11, %23, off offset:-4096\n\t"
        "global_load_dwordx4 %12, %17, off\n\t"
        "global_load_dwordx4 %13, %19, off\n\t"
        "global_load_dwordx4 %14, %21, off\n\t"
        "global_load_dwordx4 %15, %23, off"
        : "=&v"(w0), "=&v"(i0), "=&v"(v0), "=&v"(x0),
          "=&v"(w1), "=&v"(i1), "=&v"(v1), "=&v"(x1),
          "=&v"(w2), "=&v"(i2), "=&v"(v2), "=&v"(x2),
          "=&v"(w3), "=&v"(i3), "=&v"(v3), "=&v"(x3)
        : "v"(wb0), "v"(wb1), "v"(ib0), "v"(ib1),
          "v"(vb0), "v"(vb1), "v"(xb0), "v"(xb1));

    float sum = 0.0f;

    asm volatile("s_waitcnt vmcnt(12)" ::: "memory");
    __builtin_amdgcn_sched_barrier(0);
    sum += contrib(w0.x, i0.x, v0.x, x0.x) + contrib(w0.y, i0.y, v0.y, x0.y)
         + contrib(w0.z, i0.z, v0.z, x0.z) + contrib(w0.w, i0.w, v0.w, x0.w);

    asm volatile("s_waitcnt vmcnt(8)" ::: "memory");
    __builtin_amdgcn_sched_barrier(0);
    sum += contrib(w1.x, i1.x, v1.x, x1.x) + contrib(w1.y, i1.y, v1.y, x1.y)
         + contrib(w1.z, i1.z, v1.z, x1.z) + contrib(w1.w, i1.w, v1.w, x1.w);

    asm volatile("s_waitcnt vmcnt(4)" ::: "memory");
    __builtin_amdgcn_sched_barrier(0);
    sum += contrib(w2.x, i2.x, v2.x, x2.x) + contrib(w2.y, i2.y, v2.y, x2.y)
         + contrib(w2.z, i2.z, v2.z, x2.z) + contrib(w2.w, i2.w, v2.w, x2.w);

    asm volatile("s_waitcnt vmcnt(0)" ::: "memory");
    __builtin_amdgcn_sched_barrier(0);
    sum += contrib(w3.x, i3.x, v3.x, x3.x) + contrib(w3.y, i3.y, v3.y, x3.y)
         + contrib(w3.z, i3.z, v3.z, x3.z) + contrib(w3.w, i3.w, v3.w, x3.w);

    // wave-level butterfly reduce (64 lanes)
    #pragma unroll
    for (int off = 32; off > 0; off >>= 1)
        sum += __shfl_down(sum, off);

    // cross-wave reduce via 4-slot LDS
    __shared__ float wsum[4];
    if (lane == 0) wsum[wave] = sum;
    __syncthreads();

    if (tid == 0) {
        const float rb = (float)(__brev((unsigned)rng_bias_idx[row]) >> 24);
        const float b_bit = (buf_bias[row] >= rb) ? 1.0f : 0.0f;
        const float total = acc[row] + wsum[0] + wsum[1] + wsum[2] + wsum[3] + b_bit;
        out[row] = (total >= acc_bound[0]) ? 1.0f : 0.0f;
    }
}

extern "C" void kernel_launch(void* const* d_in, const int* in_sizes, int n_in,
                              void* d_out, int out_size, void* d_ws, size_t ws_size,
                              hipStream_t stream)
{
    // setup_inputs() order:
    // 0:x 1:buf_wght 2:buf_bias 3:rng 4:acc 5:acc_bound
    // 6:rng_wght_idx 7:rng_bias_idx 8:rng_wght_idx_inv
    const float* x         = (const float*)d_in[0];
    const float* buf_wght  = (const float*)d_in[1];
    const float* buf_bias  = (const float*)d_in[2];
    // d_in[3] = rng table — unused (closed form: rng[i] == bitreverse8(i))
    const float* acc       = (const float*)d_in[4];
    const float* acc_bound = (const float*)d_in[5];
    const int*   rwi       = (const int*)d_in[6];
    const int*   rbi       = (const int*)d_in[7];
    const int*   rwii      = (const int*)d_in[8];
    float* out = (float*)d_out;

    dim3 grid(OUT_F);       // 4096 blocks: 1 row per block
    dim3 block(256);
    hipLaunchKernelGGL(unary_linear_kernel, grid, block, 0, stream,
                       x, buf_wght, buf_bias, acc, acc_bound,
                       rwi, rbi, rwii, out);
}